// Round 6
// baseline (22085.400 us; speedup 1.0000x reference)
//
#include <hip/hip_runtime.h>

// ---------------- problem dims ----------------
constexpr int BB = 16;       // batch
constexpr int TT = 256;      // seq len
constexpr int IN0 = 512;     // input dim (layer 0)
constexpr int HH = 1024;     // hidden
constexpr int GG = 4096;     // 4*H gates
constexpr int NLAYERS = 8;
constexpr int NWG = 256;     // scan workgroups (1 per CU)

// ---------------- ws layout (bytes) ----------------
constexpr size_t XG_OFF  = 0;                        // xg2 [t][b][4096] : 64 MB
constexpr size_t HSA_OFF = 67108864;                 // 16 MB
constexpr size_t HSB_OFF = HSA_OFF + 16777216;       // 16 MB
constexpr size_t HG2_OFF = HSB_OFF + 16777216;       // h ping-pong: 2 x [16 chunk][16 b][64] = 128 KB
constexpr size_t FC1_OFF = HG2_OFF + 131072;         // 32 KB
constexpr size_t FC2_OFF = FC1_OFF + 32768;          // 16 KB
constexpr size_t BAR_OFF = FC2_OFF + 16384;          // gdone[16] monotonic counters @ 64B stride

// ---------------- scan LDS float offsets ----------------
constexpr int WT_F = 0;        // 17440 floats
constexpr int HB_F = 17440;    // 17472 floats
constexpr int PART_F = 34912;  // 1024 floats  [wave][16r][16b]
constexpr int GV_F = 35936;    // 256 floats   [16r][16b]
constexpr int SMEM_FLOATS = 36192;
constexpr int SMEM_BYTES = SMEM_FLOATS * 4;   // 144,768 B

// ---------------- GEMM: xg2[(t*16+b)*4096+n] = X[m]·W[n] + bih[n]+bhh[n], m=b*256+t
__global__ __launch_bounds__(256) void gemm_xg(const float* __restrict__ X,
                                               const float* __restrict__ W,
                                               const float* __restrict__ bih,
                                               const float* __restrict__ bhh,
                                               float* __restrict__ out, int K)
{
    __shared__ float Xs[64][33];
    __shared__ float Ws[64][33];
    const int tid = threadIdx.x;
    const int tm = tid >> 4, tn = tid & 15;
    const int m0 = blockIdx.y * 64, n0 = blockIdx.x * 64;
    float acc[4][4] = {};

    for (int k0 = 0; k0 < K; k0 += 32) {
#pragma unroll
        for (int i = 0; i < 2; ++i) {
            int f = tid + i * 256;
            int row = f >> 3, c4 = (f & 7) << 2;
            float4 xv = *(const float4*)(X + (size_t)(m0 + row) * K + k0 + c4);
            float4 wv = *(const float4*)(W + (size_t)(n0 + row) * K + k0 + c4);
            Xs[row][c4 + 0] = xv.x; Xs[row][c4 + 1] = xv.y;
            Xs[row][c4 + 2] = xv.z; Xs[row][c4 + 3] = xv.w;
            Ws[row][c4 + 0] = wv.x; Ws[row][c4 + 1] = wv.y;
            Ws[row][c4 + 2] = wv.z; Ws[row][c4 + 3] = wv.w;
        }
        __syncthreads();
#pragma unroll 4
        for (int kk = 0; kk < 32; ++kk) {
            float xr[4], wc[4];
#pragma unroll
            for (int i = 0; i < 4; ++i) xr[i] = Xs[tm * 4 + i][kk];
#pragma unroll
            for (int j = 0; j < 4; ++j) wc[j] = Ws[tn * 4 + j][kk];
#pragma unroll
            for (int i = 0; i < 4; ++i)
#pragma unroll
                for (int j = 0; j < 4; ++j)
                    acc[i][j] = fmaf(xr[i], wc[j], acc[i][j]);
        }
        __syncthreads();
    }

    const int n = n0 + tn * 4;
    const float4 bi = *(const float4*)(bih + n);
    const float4 bh = *(const float4*)(bhh + n);
    const float4 bias = {bi.x + bh.x, bi.y + bh.y, bi.z + bh.z, bi.w + bh.w};
#pragma unroll
    for (int i = 0; i < 4; ++i) {
        int m = m0 + tm * 4 + i;
        int bb = m >> 8, tt = m & 255;
        float4 o = {acc[i][0] + bias.x, acc[i][1] + bias.y,
                    acc[i][2] + bias.z, acc[i][3] + bias.w};
        *(float4*)(out + (size_t)(tt * 16 + bb) * GG + n) = o;
    }
}

__device__ __forceinline__ float sigf(float x) { return 1.0f / (1.0f + expf(-x)); }

// ---------------- per-layer LSTM scan (persistent, per-chunk flag sync) ----------------
// WG wg owns h-cols j0=4wg..4wg+3 -> 16 gate rows grow(r)=(r>>2)*1024+j0+(r&3)
// wave w consumes chunks 4w..4w+3.  Chunk g produced by WGs 16g..16g+15.
// gdone[g]: monotonic counter, +1 per producer WG per step. Ready for step t
// when gdone[g] >= 16*(TT*layer + t).  h ping-pongs between parity buffers.
__global__ __launch_bounds__(256, 1) void lstm_scan(const float* __restrict__ Whh,
                                                    const float* __restrict__ xg,
                                                    float* __restrict__ hseq,
                                                    float* __restrict__ hglob2,
                                                    unsigned* __restrict__ gdone,
                                                    unsigned wantbase)
{
    extern __shared__ float smem[];
    float4* sm4 = (float4*)smem;

    const int tid = threadIdx.x;
    const int wg  = blockIdx.x;
    const int j0  = wg << 2;
    const int w   = tid >> 6;
    const int ln  = tid & 63;

    // ---- stage Whh tile once
    {
        const int r = tid >> 4, m = tid & 15;
        const int grow = ((r >> 2) << 10) + j0 + (r & 3);
        const float4* wsrc = (const float4*)Whh + (size_t)grow * 256 + m;
        float4* wdst = sm4 + r * 272 + 2 * (r >> 2) + m;
#pragma unroll
        for (int q = 0; q < 16; ++q)
            wdst[q * 17] = wsrc[q * 16];
    }

    // lane decomposition for the dot
    const int kg = ln >> 4, rg = (ln >> 2) & 3, bg4 = ln & 3;
    const int blk = (w << 2) + kg;
    int Wb[4], Hb[4];
#pragma unroll
    for (int i = 0; i < 4; ++i)
        Wb[i] = (4 * rg + i) * 272 + 2 * rg + blk * 17;
#pragma unroll
    for (int j = 0; j < 4; ++j)
        Hb[j] = (HB_F >> 2) + blk * 273 + (4 * bg4 + j) * 17;

    const int sb_hi = ln >> 4, sm_lo = ln & 15;

    const int r_red = tid >> 4, b_red = tid & 15;
    const int grow_red = ((r_red >> 2) << 10) + j0 + (r_red & 3);
    const int jl = tid >> 4, bg = tid & 15;      // for tid<64

    unsigned* myg = gdone + ((wg >> 4) << 4);    // this WG's produced chunk

    float c_state = 0.0f;
    __syncthreads();

    float xg_pref = xg[(size_t)(0 * 16 + b_red) * GG + grow_red];

    for (int t = 0; t < TT; ++t) {
        float acc[4][4] = {};

        if (t > 0) {
            // ---- wait: this wave's 4 input chunks published for step t
            const unsigned want = wantbase + 16u * (unsigned)t;
            if (ln == 0) {
#pragma unroll
                for (int c = 0; c < 4; ++c) {
                    unsigned* p = gdone + (((w << 2) + c) << 4);
                    while (__hip_atomic_load(p, __ATOMIC_RELAXED, __HIP_MEMORY_SCOPE_AGENT) < want)
                        __builtin_amdgcn_s_sleep(1);
                }
            }
            __builtin_amdgcn_wave_barrier();

            // h(t-1) from parity buffer: device-coherent loads -> regs -> LDS
            const float4* hload = (const float4*)hglob2 + (((t - 1) & 1) << 12);
            float4 v[4][4];
#pragma unroll
            for (int c = 0; c < 4; ++c) {
                const float4* p = hload + ((w << 2) + c) * 256 + ln;
                asm volatile(
                    "global_load_dwordx4 %0, %4, off sc0 sc1\n\t"
                    "global_load_dwordx4 %1, %4, off offset:1024 sc0 sc1\n\t"
                    "global_load_dwordx4 %2, %4, off offset:2048 sc0 sc1\n\t"
                    "global_load_dwordx4 %3, %4, off offset:3072 sc0 sc1"
                    : "=&v"(v[c][0]), "=&v"(v[c][1]), "=&v"(v[c][2]), "=&v"(v[c][3])
                    : "v"(p) : "memory");
            }
            asm volatile("s_waitcnt vmcnt(0)" ::: "memory");
            __builtin_amdgcn_sched_barrier(0);
#pragma unroll
            for (int c = 0; c < 4; ++c)
#pragma unroll
                for (int i = 0; i < 4; ++i)
                    sm4[(HB_F >> 2) + ((w << 2) + c) * 273 + ((i << 2) + sb_hi) * 17 + sm_lo] = v[c][i];
            asm volatile("s_waitcnt lgkmcnt(0)" ::: "memory");
            __builtin_amdgcn_wave_barrier();

            // ---- dot: 16 k4-iters, 8 b128 reads + 64 fma each
#pragma unroll 4
            for (int k4 = 0; k4 < 16; ++k4) {
                float4 wv[4], hv[4];
#pragma unroll
                for (int i = 0; i < 4; ++i) wv[i] = sm4[Wb[i] + k4];
#pragma unroll
                for (int j = 0; j < 4; ++j) hv[j] = sm4[Hb[j] + k4];
#pragma unroll
                for (int i = 0; i < 4; ++i)
#pragma unroll
                    for (int j = 0; j < 4; ++j) {
                        acc[i][j] = fmaf(wv[i].x, hv[j].x, acc[i][j]);
                        acc[i][j] = fmaf(wv[i].y, hv[j].y, acc[i][j]);
                        acc[i][j] = fmaf(wv[i].z, hv[j].z, acc[i][j]);
                        acc[i][j] = fmaf(wv[i].w, hv[j].w, acc[i][j]);
                    }
            }
            // ---- k-butterfly across kg (lane bits 4,5)
#pragma unroll
            for (int i = 0; i < 4; ++i)
#pragma unroll
                for (int j = 0; j < 4; ++j) {
                    float vv = acc[i][j];
                    vv += __shfl_xor(vv, 16);
                    vv += __shfl_xor(vv, 32);
                    acc[i][j] = vv;
                }
        }

        if (ln < 16) {   // kg==0 lanes hold full per-wave k-slice sums
            const int rg0 = ln >> 2, bg0 = ln & 3;
#pragma unroll
            for (int i = 0; i < 4; ++i)
#pragma unroll
                for (int j = 0; j < 4; ++j)
                    smem[PART_F + (w << 8) + (4 * rg0 + i) * 16 + 4 * bg0 + j] = acc[i][j];
        }
        __syncthreads();

        smem[GV_F + tid] = smem[PART_F + tid] + smem[PART_F + 256 + tid] +
                           smem[PART_F + 512 + tid] + smem[PART_F + 768 + tid] + xg_pref;
        __syncthreads();

        float hval = 0.f;
        int col = 0;
        if (tid < 64) {
            col = j0 + jl;
            float iv = smem[GV_F + (jl     ) * 16 + bg];
            float fv = smem[GV_F + (jl +  4) * 16 + bg];
            float gg = smem[GV_F + (jl +  8) * 16 + bg];
            float ov = smem[GV_F + (jl + 12) * 16 + bg];
            c_state = sigf(fv) * c_state + sigf(iv) * tanhf(gg);
            hval = sigf(ov) * tanhf(c_state);
            // device-coherent store into parity buffer t&1
            float* hdst = hglob2 + ((size_t)(t & 1) << 14) +
                          ((col >> 6) << 10) + (bg << 6) + (col & 63);
            asm volatile("global_store_dword %0, %1, off sc0 sc1"
                         :: "v"(hdst), "v"(hval) : "memory");
        }
        if (tid == 0) {
            // release: wave 0's h stores acked at coherence point, then publish
            asm volatile("s_waitcnt vmcnt(0)" ::: "memory");
            __hip_atomic_fetch_add(myg, 1u, __ATOMIC_RELAXED, __HIP_MEMORY_SCOPE_AGENT);
        }
        // off critical path: next-layer GEMM input + next-step xg prefetch
        if (tid < 64)
            hseq[(size_t)(bg * TT + t) * HH + col] = hval;
        if (t + 1 < TT)
            xg_pref = xg[(size_t)((t + 1) * 16 + b_red) * GG + grow_red];
    }
}

// ---------------- FC head ----------------
__global__ void fc_relu(const float* __restrict__ in, const float* __restrict__ w,
                        const float* __restrict__ b, float* __restrict__ out,
                        int N, int K, int instride, int do_relu)
{
    int g = blockIdx.x * blockDim.x + threadIdx.x;
    if (g >= BB * N) return;
    int bi = g / N, n = g - bi * N;
    const float* ip = in + (size_t)bi * instride;
    const float* wp = w + (size_t)n * K;
    float s = 0.f;
    for (int k = 0; k < K; k += 4) {
        float4 a = *(const float4*)(ip + k);
        float4 q = *(const float4*)(wp + k);
        s += a.x * q.x + a.y * q.y + a.z * q.z + a.w * q.w;
    }
    s += b[n];
    if (do_relu) s = fmaxf(s, 0.f);
    out[g] = s;
}

// ---------------- launch ----------------
extern "C" void kernel_launch(void* const* d_in, const int* in_sizes, int n_in,
                              void* d_out, int out_size, void* d_ws, size_t ws_size,
                              hipStream_t stream)
{
    const float* x    = (const float*)d_in[0];
    const float* Wih0 = (const float*)d_in[1];
    const float* WihR = (const float*)d_in[2];
    const float* Whh  = (const float*)d_in[3];
    const float* bih  = (const float*)d_in[4];
    const float* bhh  = (const float*)d_in[5];
    const float* fc1w = (const float*)d_in[6];
    const float* fc1b = (const float*)d_in[7];
    const float* fc2w = (const float*)d_in[8];
    const float* fc2b = (const float*)d_in[9];
    const float* fc3w = (const float*)d_in[10];
    const float* fc3b = (const float*)d_in[11];
    float* out = (float*)d_out;
    char* ws = (char*)d_ws;

    float* xg     = (float*)(ws + XG_OFF);
    float* hsA    = (float*)(ws + HSA_OFF);
    float* hsB    = (float*)(ws + HSB_OFF);
    float* hglob2 = (float*)(ws + HG2_OFF);
    float* fc1o   = (float*)(ws + FC1_OFF);
    float* fc2o   = (float*)(ws + FC2_OFF);
    unsigned* gdone = (unsigned*)(ws + BAR_OFF);

    (void)hipFuncSetAttribute((const void*)lstm_scan,
                              hipFuncAttributeMaxDynamicSharedMemorySize, SMEM_BYTES);
    (void)hipMemsetAsync(ws + BAR_OFF, 0, 2048, stream);   // gdone = 0 (monotonic across layers)

    for (int l = 0; l < NLAYERS; ++l) {
        const float* X  = (l == 0) ? x : ((l & 1) ? hsA : hsB);
        const int K     = (l == 0) ? IN0 : HH;
        const float* Wl = (l == 0) ? Wih0 : (WihR + (size_t)(l - 1) * GG * HH);
        gemm_xg<<<dim3(GG / 64, (BB * TT) / 64), 256, 0, stream>>>(
            X, Wl, bih + (size_t)l * GG, bhh + (size_t)l * GG, xg, K);

        float* hout = (l & 1) ? hsB : hsA;
        const float* whh_l = Whh + (size_t)l * GG * HH;
        unsigned wantbase = (unsigned)(16 * TT * l);
        void* args[6] = {(void*)&whh_l, (void*)&xg, (void*)&hout,
                         (void*)&hglob2, (void*)&gdone, (void*)&wantbase};
        hipError_t e = hipLaunchCooperativeKernel((void*)lstm_scan, dim3(NWG), dim3(256),
                                                  args, SMEM_BYTES, stream);
        if (e != hipSuccess) {
            lstm_scan<<<dim3(NWG), dim3(256), SMEM_BYTES, stream>>>(
                whh_l, xg, hout, hglob2, gdone, wantbase);
        }
    }

    const float* hlast = hsB + (size_t)255 * HH;
    fc_relu<<<32, 256, 0, stream>>>(hlast, fc1w, fc1b, fc1o, 512, 1024, TT * HH, 1);
    fc_relu<<<16, 256, 0, stream>>>(fc1o, fc2w, fc2b, fc2o, 256, 512, 512, 1);
    fc_relu<<<1, 16, 0, stream>>>(fc2o, fc3w, fc3b, out, 1, 256, 256, 0);
}

// Round 7
// 14999.420 us; speedup vs baseline: 1.4724x; 1.4724x over previous
//
#include <hip/hip_runtime.h>

// ---------------- problem dims ----------------
constexpr int BB = 16;       // batch
constexpr int TT = 256;      // seq len
constexpr int IN0 = 512;     // input dim (layer 0)
constexpr int HH = 1024;     // hidden
constexpr int GG = 4096;     // 4*H gates
constexpr int NLAYERS = 8;
constexpr int NWG = 256;     // scan workgroups (1 per CU)

// ---------------- ws layout (bytes) ----------------
constexpr size_t XG_OFF  = 0;                        // xg2 [t][b][4096] : 64 MB
constexpr size_t HSA_OFF = 67108864;                 // 16 MB
constexpr size_t HSB_OFF = HSA_OFF + 16777216;       // 16 MB
constexpr size_t HG2_OFF = HSB_OFF + 16777216;       // h parity: 2 x [16 chunk][16 b][64] = 128 KB
constexpr size_t FC1_OFF = HG2_OFF + 131072;         // 32 KB
constexpr size_t FC2_OFF = FC1_OFF + 32768;          // 16 KB
constexpr size_t BAR_OFF = FC2_OFF + 16384;          // barrier state (4 KB)
// bar (unsigned): arrive[g] @ g*16 (g<16); root @ 256; gen copy[g] @ 512+g*16

// ---------------- scan LDS (bytes/floats) ----------------
// h-hi blocks: [kk 0..127][b 0..15] 16B blocks, kk-row stride 272B (16B pad)
constexpr int HHI_B = 0;           // 34,816 B
constexpr int HLO_B = 34816;       // 34,816 B
constexpr int PART_F = 17408;      // float idx (= byte 69,632): [4 waves][16 r pad17]
constexpr int GV_F = 18496;        // 256 floats
constexpr int SMEM_BYTES = 90112;  // 75,008 used; padded >80K to force 1 WG/CU

typedef __attribute__((ext_vector_type(8))) short bf16x8;
typedef __attribute__((ext_vector_type(4))) float f32x4;

__device__ __forceinline__ unsigned short f2bf(float f)
{
    union { float f; unsigned u; } v{f};
    unsigned r = v.u + 0x7FFFu + ((v.u >> 16) & 1u);   // RNE
    return (unsigned short)(r >> 16);
}
__device__ __forceinline__ float bf2f(unsigned short h)
{
    union { unsigned u; float f; } v{(unsigned)h << 16};
    return v.f;
}

// ---------------- GEMM: xg2[(t*16+b)*4096+n] = X[m]·W[n] + bih[n]+bhh[n], m=b*256+t
__global__ __launch_bounds__(256) void gemm_xg(const float* __restrict__ X,
                                               const float* __restrict__ W,
                                               const float* __restrict__ bih,
                                               const float* __restrict__ bhh,
                                               float* __restrict__ out, int K)
{
    __shared__ float Xs[64][33];
    __shared__ float Ws[64][33];
    const int tid = threadIdx.x;
    const int tm = tid >> 4, tn = tid & 15;
    const int m0 = blockIdx.y * 64, n0 = blockIdx.x * 64;
    float acc[4][4] = {};

    for (int k0 = 0; k0 < K; k0 += 32) {
#pragma unroll
        for (int i = 0; i < 2; ++i) {
            int f = tid + i * 256;
            int row = f >> 3, c4 = (f & 7) << 2;
            float4 xv = *(const float4*)(X + (size_t)(m0 + row) * K + k0 + c4);
            float4 wv = *(const float4*)(W + (size_t)(n0 + row) * K + k0 + c4);
            Xs[row][c4 + 0] = xv.x; Xs[row][c4 + 1] = xv.y;
            Xs[row][c4 + 2] = xv.z; Xs[row][c4 + 3] = xv.w;
            Ws[row][c4 + 0] = wv.x; Ws[row][c4 + 1] = wv.y;
            Ws[row][c4 + 2] = wv.z; Ws[row][c4 + 3] = wv.w;
        }
        __syncthreads();
#pragma unroll 4
        for (int kk = 0; kk < 32; ++kk) {
            float xr[4], wc[4];
#pragma unroll
            for (int i = 0; i < 4; ++i) xr[i] = Xs[tm * 4 + i][kk];
#pragma unroll
            for (int j = 0; j < 4; ++j) wc[j] = Ws[tn * 4 + j][kk];
#pragma unroll
            for (int i = 0; i < 4; ++i)
#pragma unroll
                for (int j = 0; j < 4; ++j)
                    acc[i][j] = fmaf(xr[i], wc[j], acc[i][j]);
        }
        __syncthreads();
    }

    const int n = n0 + tn * 4;
    const float4 bi = *(const float4*)(bih + n);
    const float4 bh = *(const float4*)(bhh + n);
    const float4 bias = {bi.x + bh.x, bi.y + bh.y, bi.z + bh.z, bi.w + bh.w};
#pragma unroll
    for (int i = 0; i < 4; ++i) {
        int m = m0 + tm * 4 + i;
        int bb = m >> 8, tt = m & 255;
        float4 o = {acc[i][0] + bias.x, acc[i][1] + bias.y,
                    acc[i][2] + bias.z, acc[i][3] + bias.w};
        *(float4*)(out + (size_t)(tt * 16 + bb) * GG + n) = o;
    }
}

__device__ __forceinline__ float sigf(float x) { return 1.0f / (1.0f + expf(-x)); }

// ---------------- per-layer LSTM scan: MFMA split-bf16 dot, tree barrier ----------------
// WG wg owns h-cols j0=4wg..4wg+3 -> 16 gate rows grow(r)=(r>>2)*1024+j0+(r&3)
// wave w owns K-slice [256w,256w+256); per step computes one 16x16 MFMA partial.
__global__ __launch_bounds__(256, 1) void lstm_scan(const float* __restrict__ Whh,
                                                    const float* __restrict__ xg,
                                                    float* __restrict__ hseq,
                                                    float* __restrict__ hglob2,
                                                    unsigned* __restrict__ bar,
                                                    unsigned wantbase)
{
    extern __shared__ float smem[];
    char* smb = (char*)smem;

    const int tid = threadIdx.x;
    const int wg  = blockIdx.x;
    const int j0  = wg << 2;
    const int w   = tid >> 6;
    const int ln  = tid & 63;
    const int m   = ln & 15;     // A-row / B-col lane index
    const int kq  = ln >> 4;     // k-quarter within a K=32 MFMA tile

    // ---- preload W fragments into registers (step-invariant): 8 ksteps x (hi,lo)
    bf16x8 wf_hi[8], wf_lo[8];
    {
        const int grow = ((m >> 2) << 10) + j0 + (m & 3);
        const float* wrow = Whh + (size_t)grow * 1024 + (w << 8) + (kq << 3);
#pragma unroll
        for (int s = 0; s < 8; ++s) {
            float4 f0 = *(const float4*)(wrow + s * 32);
            float4 f1 = *(const float4*)(wrow + s * 32 + 4);
            float fv[8] = {f0.x, f0.y, f0.z, f0.w, f1.x, f1.y, f1.z, f1.w};
            bf16x8 h8, l8;
#pragma unroll
            for (int i = 0; i < 8; ++i) {
                unsigned short hb = f2bf(fv[i]);
                float r = fv[i] - bf2f(hb);
                h8[i] = (short)hb;
                l8[i] = (short)f2bf(r);
            }
            wf_hi[s] = h8;
            wf_lo[s] = l8;
        }
    }

    // staging lane mapping (h split)
    const int bidx = ln >> 4;            // b high bits
    const int jj   = ln & 15;            // j-quad
    const int kkloc = jj >> 1;           // octet within chunk
    const int sub   = (jj & 1) * 8;      // byte offset within 16B block

    const int r_red = tid >> 4, b_red = tid & 15;
    const int grow_red = ((r_red >> 2) << 10) + j0 + (r_red & 3);
    const int jl = tid >> 4, bg = tid & 15;      // gate lanes (tid<64)

    // barrier pointers (tid0 use)
    unsigned* arr  = bar + ((wg >> 4) << 4);
    unsigned* root = bar + 256;
    unsigned* genc = bar + 512 + ((wg >> 4) << 4);

    float c_state = 0.0f;

    float xg_pref = xg[(size_t)(0 * 16 + b_red) * GG + grow_red];

    for (int t = 0; t < TT; ++t) {
        f32x4 asum = {0.f, 0.f, 0.f, 0.f};

        if (t > 0) {
            // h(t-1) from parity buffer: device-coherent loads -> regs
            const float4* hload = (const float4*)hglob2 + (((t - 1) & 1) << 12);
            float4 v[4][4];
#pragma unroll
            for (int c = 0; c < 4; ++c) {
                const float4* p = hload + ((w << 2) + c) * 256 + ln;
                asm volatile(
                    "global_load_dwordx4 %0, %4, off sc0 sc1\n\t"
                    "global_load_dwordx4 %1, %4, off offset:1024 sc0 sc1\n\t"
                    "global_load_dwordx4 %2, %4, off offset:2048 sc0 sc1\n\t"
                    "global_load_dwordx4 %3, %4, off offset:3072 sc0 sc1"
                    : "=&v"(v[c][0]), "=&v"(v[c][1]), "=&v"(v[c][2]), "=&v"(v[c][3])
                    : "v"(p) : "memory");
            }
            asm volatile("s_waitcnt vmcnt(0)" ::: "memory");
            __builtin_amdgcn_sched_barrier(0);

            // split fp32 -> bf16 hi/lo, write octet blocks [kk][b] (wave-private region)
#pragma unroll
            for (int c = 0; c < 4; ++c) {
                const int kk = ((w << 2) + c) * 8 + kkloc;
#pragma unroll
                for (int i = 0; i < 4; ++i) {
                    const int b = (i << 2) + bidx;
                    float4 vv = v[c][i];
                    unsigned short h0 = f2bf(vv.x), h1 = f2bf(vv.y),
                                   h2 = f2bf(vv.z), h3 = f2bf(vv.w);
                    float r0 = vv.x - bf2f(h0), r1 = vv.y - bf2f(h1),
                          r2 = vv.z - bf2f(h2), r3 = vv.w - bf2f(h3);
                    uint2 uh = {(unsigned)h0 | ((unsigned)h1 << 16),
                                (unsigned)h2 | ((unsigned)h3 << 16)};
                    uint2 ul = {(unsigned)f2bf(r0) | ((unsigned)f2bf(r1) << 16),
                                (unsigned)f2bf(r2) | ((unsigned)f2bf(r3) << 16)};
                    char* base = smb + kk * 272 + b * 16 + sub;
                    *(uint2*)(base) = uh;
                    *(uint2*)(base + HLO_B) = ul;
                }
            }
            asm volatile("s_waitcnt lgkmcnt(0)" ::: "memory");
            __builtin_amdgcn_sched_barrier(0);
            __builtin_amdgcn_wave_barrier();

            // ---- MFMA: 8 ksteps x 3 (hi*hi + hi*lo + lo*hi), 3 indep acc chains
            f32x4 aA = {0.f, 0.f, 0.f, 0.f};
            f32x4 aB = {0.f, 0.f, 0.f, 0.f};
            f32x4 aC = {0.f, 0.f, 0.f, 0.f};
            const char* hb0 = smb + ((w << 5) + kq) * 272 + m * 16;
#pragma unroll
            for (int s = 0; s < 8; ++s) {
                bf16x8 bh = *(const bf16x8*)(hb0 + s * 1088);
                bf16x8 bl = *(const bf16x8*)(hb0 + HLO_B + s * 1088);
                aA = __builtin_amdgcn_mfma_f32_16x16x32_bf16(wf_hi[s], bh, aA, 0, 0, 0);
                aB = __builtin_amdgcn_mfma_f32_16x16x32_bf16(wf_hi[s], bl, aB, 0, 0, 0);
                aC = __builtin_amdgcn_mfma_f32_16x16x32_bf16(wf_lo[s], bh, aC, 0, 0, 0);
            }
            asum = aA + aB;
            asum = asum + aC;
        }

        // partials: D row=(kq*4+r), col=m  ->  part[w][row][col] (pad 17)
#pragma unroll
        for (int r = 0; r < 4; ++r)
            smem[PART_F + w * 272 + ((kq << 2) + r) * 17 + m] = asum[r];
        __syncthreads();

        smem[GV_F + tid] = smem[PART_F + (tid >> 4) * 17 + (tid & 15)]
                         + smem[PART_F + 272 + (tid >> 4) * 17 + (tid & 15)]
                         + smem[PART_F + 544 + (tid >> 4) * 17 + (tid & 15)]
                         + smem[PART_F + 816 + (tid >> 4) * 17 + (tid & 15)]
                         + xg_pref;
        __syncthreads();

        // prefetch next step's xg (hides under gates + barrier)
        float xg_next = 0.f;
        if (t + 1 < TT)
            xg_next = xg[(size_t)((t + 1) * 16 + b_red) * GG + grow_red];

        if (tid < 64) {
            const int col = j0 + jl;
            float iv = smem[GV_F + (jl     ) * 16 + bg];
            float fv = smem[GV_F + (jl +  4) * 16 + bg];
            float gg = smem[GV_F + (jl +  8) * 16 + bg];
            float ov = smem[GV_F + (jl + 12) * 16 + bg];
            c_state = sigf(fv) * c_state + sigf(iv) * tanhf(gg);
            float hval = sigf(ov) * tanhf(c_state);
            // device-coherent store into parity buffer t&1
            float* hdst = hglob2 + ((size_t)(t & 1) << 14) +
                          ((col >> 6) << 10) + (bg << 6) + (col & 63);
            asm volatile("global_store_dword %0, %1, off sc0 sc1"
                         :: "v"(hdst), "v"(hval) : "memory");
            hseq[(size_t)(bg * TT + t) * HH + col] = hval;   // next-layer GEMM input
        }

        if (t < TT - 1) {
            const unsigned target = wantbase + (unsigned)t + 1u;
            if (tid == 0) {
                // release: wave-0 h stores acked at coherence point before arrive
                asm volatile("s_waitcnt vmcnt(0)" ::: "memory");
                unsigned a = __hip_atomic_fetch_add(arr, 1u, __ATOMIC_RELAXED, __HIP_MEMORY_SCOPE_AGENT);
                if (a == 15u) {
                    unsigned ra = __hip_atomic_fetch_add(root, 1u, __ATOMIC_RELAXED, __HIP_MEMORY_SCOPE_AGENT);
                    if (ra == 15u) {
                        __hip_atomic_store(root, 0u, __ATOMIC_RELAXED, __HIP_MEMORY_SCOPE_AGENT);
#pragma unroll
                        for (int i = 0; i < 16; ++i)
                            __hip_atomic_store(bar + (i << 4), 0u, __ATOMIC_RELAXED, __HIP_MEMORY_SCOPE_AGENT);
                        asm volatile("s_waitcnt vmcnt(0)" ::: "memory");
#pragma unroll
                        for (int i = 0; i < 16; ++i)
                            __hip_atomic_store(bar + 512 + (i << 4), target,
                                               __ATOMIC_RELAXED, __HIP_MEMORY_SCOPE_AGENT);
                    }
                }
                while (__hip_atomic_load(genc, __ATOMIC_RELAXED, __HIP_MEMORY_SCOPE_AGENT) < target)
                    __builtin_amdgcn_s_sleep(1);
            }
            __syncthreads();
        }
        xg_pref = xg_next;
    }
}

// ---------------- FC head ----------------
__global__ void fc_relu(const float* __restrict__ in, const float* __restrict__ w,
                        const float* __restrict__ b, float* __restrict__ out,
                        int N, int K, int instride, int do_relu)
{
    int g = blockIdx.x * blockDim.x + threadIdx.x;
    if (g >= BB * N) return;
    int bi = g / N, n = g - bi * N;
    const float* ip = in + (size_t)bi * instride;
    const float* wp = w + (size_t)n * K;
    float s = 0.f;
    for (int k = 0; k < K; k += 4) {
        float4 a = *(const float4*)(ip + k);
        float4 q = *(const float4*)(wp + k);
        s += a.x * q.x + a.y * q.y + a.z * q.z + a.w * q.w;
    }
    s += b[n];
    if (do_relu) s = fmaxf(s, 0.f);
    out[g] = s;
}

// ---------------- launch ----------------
extern "C" void kernel_launch(void* const* d_in, const int* in_sizes, int n_in,
                              void* d_out, int out_size, void* d_ws, size_t ws_size,
                              hipStream_t stream)
{
    const float* x    = (const float*)d_in[0];
    const float* Wih0 = (const float*)d_in[1];
    const float* WihR = (const float*)d_in[2];
    const float* Whh  = (const float*)d_in[3];
    const float* bih  = (const float*)d_in[4];
    const float* bhh  = (const float*)d_in[5];
    const float* fc1w = (const float*)d_in[6];
    const float* fc1b = (const float*)d_in[7];
    const float* fc2w = (const float*)d_in[8];
    const float* fc2b = (const float*)d_in[9];
    const float* fc3w = (const float*)d_in[10];
    const float* fc3b = (const float*)d_in[11];
    float* out = (float*)d_out;
    char* ws = (char*)d_ws;

    float* xg     = (float*)(ws + XG_OFF);
    float* hsA    = (float*)(ws + HSA_OFF);
    float* hsB    = (float*)(ws + HSB_OFF);
    float* hglob2 = (float*)(ws + HG2_OFF);
    float* fc1o   = (float*)(ws + FC1_OFF);
    float* fc2o   = (float*)(ws + FC2_OFF);
    unsigned* bar = (unsigned*)(ws + BAR_OFF);

    (void)hipFuncSetAttribute((const void*)lstm_scan,
                              hipFuncAttributeMaxDynamicSharedMemorySize, SMEM_BYTES);
    (void)hipMemsetAsync(ws + BAR_OFF, 0, 4096, stream);   // arrive/root/gen = 0 (monotonic)

    for (int l = 0; l < NLAYERS; ++l) {
        const float* X  = (l == 0) ? x : ((l & 1) ? hsA : hsB);
        const int K     = (l == 0) ? IN0 : HH;
        const float* Wl = (l == 0) ? Wih0 : (WihR + (size_t)(l - 1) * GG * HH);
        gemm_xg<<<dim3(GG / 64, (BB * TT) / 64), 256, 0, stream>>>(
            X, Wl, bih + (size_t)l * GG, bhh + (size_t)l * GG, xg, K);

        float* hout = (l & 1) ? hsB : hsA;
        const float* whh_l = Whh + (size_t)l * GG * HH;
        unsigned wantbase = (unsigned)(TT * l);
        void* args[6] = {(void*)&whh_l, (void*)&xg, (void*)&hout,
                         (void*)&hglob2, (void*)&bar, (void*)&wantbase};
        hipError_t e = hipLaunchCooperativeKernel((void*)lstm_scan, dim3(NWG), dim3(256),
                                                  args, SMEM_BYTES, stream);
        if (e != hipSuccess) {
            lstm_scan<<<dim3(NWG), dim3(256), SMEM_BYTES, stream>>>(
                whh_l, xg, hout, hglob2, bar, wantbase);
        }
    }

    const float* hlast = hsB + (size_t)255 * HH;
    fc_relu<<<32, 256, 0, stream>>>(hlast, fc1w, fc1b, fc1o, 512, 1024, TT * HH, 1);
    fc_relu<<<16, 256, 0, stream>>>(fc1o, fc2w, fc2b, fc2o, 256, 512, 512, 1);
    fc_relu<<<1, 16, 0, stream>>>(fc2o, fc3w, fc3b, out, 1, 256, 256, 0);
}

// Round 8
// 11381.357 us; speedup vs baseline: 1.9405x; 1.3179x over previous
//
#include <hip/hip_runtime.h>

// ---------------- problem dims ----------------
constexpr int BB = 16;       // batch
constexpr int TT = 256;      // seq len
constexpr int IN0 = 512;     // input dim (layer 0)
constexpr int HH = 1024;     // hidden
constexpr int GG = 4096;     // 4*H gates
constexpr int NLAYERS = 8;
constexpr int NWG = 256;     // scan workgroups (1 per CU)

// ---------------- ws layout (bytes) ----------------
constexpr size_t XG_OFF   = 0;                         // xg2 [t*16+b][4096] fp32 : 64 MB
constexpr size_t REG0_OFF = 67108864;                  // 16 MB region 0 (Wcv / hs even layers)
constexpr size_t REG1_OFF = REG0_OFF + 16777216;       // 16 MB region 1 (Xcv0 / Wcv / hs odd)
constexpr size_t HG2_OFF  = REG1_OFF + 16777216;       // h parity: 2 x 64 KB = 128 KB
constexpr size_t FC1_OFF  = HG2_OFF + 131072;
constexpr size_t FC2_OFF  = FC1_OFF + 32768;
constexpr size_t BAR_OFF  = FC2_OFF + 16384;           // barrier state (4 KB)
// bar (unsigned): arrive[g] @ g*16 (g<16); root @ 256; gen copy[g] @ 512+g*16

// ---------------- scan LDS (bytes/floats) ----------------
constexpr int HLO_B = 34816;       // h-lo blocks base (hi at 0), both [128 kk][16 b] 16B, stride 272B
constexpr int PART_F = 17408;      // float idx: [4 waves][16 r pad17]
constexpr int GV_F = 18496;        // 256 floats
constexpr int SMEM_BYTES = 90112;  // pad >80K to force 1 WG/CU

typedef __attribute__((ext_vector_type(8))) short bf16x8;
typedef __attribute__((ext_vector_type(4))) float f32x4;

__device__ __forceinline__ unsigned short f2bf(float f)
{
    union { float f; unsigned u; } v{f};
    unsigned r = v.u + 0x7FFFu + ((v.u >> 16) & 1u);   // RNE
    return (unsigned short)(r >> 16);
}
__device__ __forceinline__ float bf2f(unsigned short h)
{
    union { unsigned u; float f; } v{(unsigned)h << 16};
    return v.f;
}

// ---------------- split conversion: fp32 -> bf16 hi + bf16 lo ----------------
__global__ __launch_bounds__(256) void conv_split(const float* __restrict__ in,
                                                  ushort* __restrict__ oh,
                                                  ushort* __restrict__ ol, int n4)
{
    int g = blockIdx.x * blockDim.x + threadIdx.x;
    if (g >= n4) return;
    float4 f = ((const float4*)in)[g];
    ushort4 h, l;
    h.x = f2bf(f.x); l.x = f2bf(f.x - bf2f(h.x));
    h.y = f2bf(f.y); l.y = f2bf(f.y - bf2f(h.y));
    h.z = f2bf(f.z); l.z = f2bf(f.z - bf2f(h.z));
    h.w = f2bf(f.w); l.w = f2bf(f.w - bf2f(h.w));
    ((ushort4*)oh)[g] = h;
    ((ushort4*)ol)[g] = l;
}

// ---------------- MFMA GEMM: out[(t*16+b)*4096+n] = sum_s sum_k A_s[m][k]*B_s[n][k] + bias
// segments: s0 = Ah*Wh, s1 = Ah*Wl, s2 = Al*Wh  (ll dropped, ~2^-18)
// m = b*256+t.  128x128 tile, 4 waves, 4x4 frags of 16x16x32 bf16 MFMA, BK=64.
__global__ __launch_bounds__(256) void gemm_mfma(const ushort* __restrict__ Ah,
                                                 const ushort* __restrict__ Al,
                                                 const ushort* __restrict__ Wh,
                                                 const ushort* __restrict__ Wl,
                                                 const float* __restrict__ bih,
                                                 const float* __restrict__ bhh,
                                                 float* __restrict__ out, int K)
{
    __shared__ ushort lds[2][128 * 72];   // [0]=A tile, [1]=B tile, row pad 72
    const int tid = threadIdx.x;
    const int w = tid >> 6, ln = tid & 63;
    const int m0 = blockIdx.y * 128, n0 = blockIdx.x * 128;
    const int arow = (w >> 1) * 64, bcol = (w & 1) * 64;
    const int lm = ln & 15, lk = (ln >> 4) * 8;
    const int sr = tid >> 3, sc = (tid & 7) * 8;

    f32x4 acc[4][4] = {};

#pragma unroll
    for (int s = 0; s < 3; ++s) {
        const ushort* Asrc = (s < 2) ? Ah : Al;
        const ushort* Bsrc = (s == 1) ? Wl : Wh;
        for (int k0 = 0; k0 < K; k0 += 64) {
            __syncthreads();
#pragma unroll
            for (int i = 0; i < 4; ++i) {
                int r = sr + 32 * i;
                *(uint4*)&lds[0][r * 72 + sc] =
                    *(const uint4*)(Asrc + (size_t)(m0 + r) * K + k0 + sc);
                *(uint4*)&lds[1][r * 72 + sc] =
                    *(const uint4*)(Bsrc + (size_t)(n0 + r) * K + k0 + sc);
            }
            __syncthreads();
#pragma unroll
            for (int ks = 0; ks < 2; ++ks) {
                bf16x8 af[4], bf[4];
#pragma unroll
                for (int i = 0; i < 4; ++i)
                    af[i] = *(const bf16x8*)&lds[0][(arow + i * 16 + lm) * 72 + ks * 32 + lk];
#pragma unroll
                for (int j = 0; j < 4; ++j)
                    bf[j] = *(const bf16x8*)&lds[1][(bcol + j * 16 + lm) * 72 + ks * 32 + lk];
#pragma unroll
                for (int i = 0; i < 4; ++i)
#pragma unroll
                    for (int j = 0; j < 4; ++j)
                        acc[i][j] = __builtin_amdgcn_mfma_f32_16x16x32_bf16(
                            af[i], bf[j], acc[i][j], 0, 0, 0);
            }
        }
    }

    // epilogue: D col = ln&15, row = (ln>>4)*4 + reg (scan-verified mapping)
#pragma unroll
    for (int j = 0; j < 4; ++j) {
        const int n = n0 + bcol + j * 16 + lm;
        const float bsum = bih[n] + bhh[n];
#pragma unroll
        for (int i = 0; i < 4; ++i) {
            const int mrow = m0 + arow + i * 16 + (ln >> 4) * 4;
#pragma unroll
            for (int r = 0; r < 4; ++r) {
                const int m = mrow + r;
                const int bb = m >> 8, tt = m & 255;
                out[(size_t)(tt * 16 + bb) * GG + n] = acc[i][j][r] + bsum;
            }
        }
    }
}

__device__ __forceinline__ float sigf(float x) { return 1.0f / (1.0f + expf(-x)); }

// ---------------- per-layer LSTM scan: MFMA split-bf16 dot, tree barrier ----------------
__global__ __launch_bounds__(256, 1) void lstm_scan(const float* __restrict__ Whh,
                                                    const float* __restrict__ xg,
                                                    ushort* __restrict__ hseq_hi,
                                                    ushort* __restrict__ hseq_lo,
                                                    float* __restrict__ hglob2,
                                                    unsigned* __restrict__ bar,
                                                    unsigned wantbase)
{
    extern __shared__ float smem[];
    char* smb = (char*)smem;

    const int tid = threadIdx.x;
    const int wg  = blockIdx.x;
    const int j0  = wg << 2;
    const int w   = tid >> 6;
    const int ln  = tid & 63;
    const int m   = ln & 15;
    const int kq  = ln >> 4;

    // ---- preload W fragments (step-invariant): 8 ksteps x (hi,lo)
    bf16x8 wf_hi[8], wf_lo[8];
    {
        const int grow = ((m >> 2) << 10) + j0 + (m & 3);
        const float* wrow = Whh + (size_t)grow * 1024 + (w << 8) + (kq << 3);
#pragma unroll
        for (int s = 0; s < 8; ++s) {
            float4 f0 = *(const float4*)(wrow + s * 32);
            float4 f1 = *(const float4*)(wrow + s * 32 + 4);
            float fv[8] = {f0.x, f0.y, f0.z, f0.w, f1.x, f1.y, f1.z, f1.w};
            bf16x8 h8, l8;
#pragma unroll
            for (int i = 0; i < 8; ++i) {
                unsigned short hb = f2bf(fv[i]);
                float r = fv[i] - bf2f(hb);
                h8[i] = (short)hb;
                l8[i] = (short)f2bf(r);
            }
            wf_hi[s] = h8;
            wf_lo[s] = l8;
        }
    }

    const int bidx = ln >> 4;
    const int jj   = ln & 15;
    const int kkloc = jj >> 1;
    const int sub   = (jj & 1) * 8;

    const int r_red = tid >> 4, b_red = tid & 15;
    const int grow_red = ((r_red >> 2) << 10) + j0 + (r_red & 3);
    const int jl = tid >> 4, bg = tid & 15;      // gate lanes (tid<64)

    unsigned* arr  = bar + ((wg >> 4) << 4);
    unsigned* root = bar + 256;
    unsigned* genc = bar + 512 + ((wg >> 4) << 4);

    float c_state = 0.0f;
    float xg_pref = xg[(size_t)(0 * 16 + b_red) * GG + grow_red];

    for (int t = 0; t < TT; ++t) {
        f32x4 asum = {0.f, 0.f, 0.f, 0.f};

        if (t > 0) {
            const float4* hload = (const float4*)hglob2 + (((t - 1) & 1) << 12);
            float4 v[4][4];
#pragma unroll
            for (int c = 0; c < 4; ++c) {
                const float4* p = hload + ((w << 2) + c) * 256 + ln;
                asm volatile(
                    "global_load_dwordx4 %0, %4, off sc0 sc1\n\t"
                    "global_load_dwordx4 %1, %4, off offset:1024 sc0 sc1\n\t"
                    "global_load_dwordx4 %2, %4, off offset:2048 sc0 sc1\n\t"
                    "global_load_dwordx4 %3, %4, off offset:3072 sc0 sc1"
                    : "=&v"(v[c][0]), "=&v"(v[c][1]), "=&v"(v[c][2]), "=&v"(v[c][3])
                    : "v"(p) : "memory");
            }
            asm volatile("s_waitcnt vmcnt(0)" ::: "memory");
            __builtin_amdgcn_sched_barrier(0);

#pragma unroll
            for (int c = 0; c < 4; ++c) {
                const int kk = ((w << 2) + c) * 8 + kkloc;
#pragma unroll
                for (int i = 0; i < 4; ++i) {
                    const int b = (i << 2) + bidx;
                    float4 vv = v[c][i];
                    unsigned short h0 = f2bf(vv.x), h1 = f2bf(vv.y),
                                   h2 = f2bf(vv.z), h3 = f2bf(vv.w);
                    float r0 = vv.x - bf2f(h0), r1 = vv.y - bf2f(h1),
                          r2 = vv.z - bf2f(h2), r3 = vv.w - bf2f(h3);
                    uint2 uh = {(unsigned)h0 | ((unsigned)h1 << 16),
                                (unsigned)h2 | ((unsigned)h3 << 16)};
                    uint2 ul = {(unsigned)f2bf(r0) | ((unsigned)f2bf(r1) << 16),
                                (unsigned)f2bf(r2) | ((unsigned)f2bf(r3) << 16)};
                    char* base = smb + kk * 272 + b * 16 + sub;
                    *(uint2*)(base) = uh;
                    *(uint2*)(base + HLO_B) = ul;
                }
            }
            asm volatile("s_waitcnt lgkmcnt(0)" ::: "memory");
            __builtin_amdgcn_sched_barrier(0);
            __builtin_amdgcn_wave_barrier();

            f32x4 aA = {0.f, 0.f, 0.f, 0.f};
            f32x4 aB = {0.f, 0.f, 0.f, 0.f};
            f32x4 aC = {0.f, 0.f, 0.f, 0.f};
            const char* hb0 = smb + ((w << 5) + kq) * 272 + m * 16;
#pragma unroll
            for (int s = 0; s < 8; ++s) {
                bf16x8 bh = *(const bf16x8*)(hb0 + s * 1088);
                bf16x8 bl = *(const bf16x8*)(hb0 + HLO_B + s * 1088);
                aA = __builtin_amdgcn_mfma_f32_16x16x32_bf16(wf_hi[s], bh, aA, 0, 0, 0);
                aB = __builtin_amdgcn_mfma_f32_16x16x32_bf16(wf_hi[s], bl, aB, 0, 0, 0);
                aC = __builtin_amdgcn_mfma_f32_16x16x32_bf16(wf_lo[s], bh, aC, 0, 0, 0);
            }
            asum = aA + aB;
            asum = asum + aC;
        }

#pragma unroll
        for (int r = 0; r < 4; ++r)
            smem[PART_F + w * 272 + ((kq << 2) + r) * 17 + m] = asum[r];
        __syncthreads();

        smem[GV_F + tid] = smem[PART_F + (tid >> 4) * 17 + (tid & 15)]
                         + smem[PART_F + 272 + (tid >> 4) * 17 + (tid & 15)]
                         + smem[PART_F + 544 + (tid >> 4) * 17 + (tid & 15)]
                         + smem[PART_F + 816 + (tid >> 4) * 17 + (tid & 15)]
                         + xg_pref;
        __syncthreads();

        float xg_next = 0.f;
        if (t + 1 < TT)
            xg_next = xg[(size_t)((t + 1) * 16 + b_red) * GG + grow_red];

        if (tid < 64) {
            const int col = j0 + jl;
            float iv = smem[GV_F + (jl     ) * 16 + bg];
            float fv = smem[GV_F + (jl +  4) * 16 + bg];
            float gg = smem[GV_F + (jl +  8) * 16 + bg];
            float ov = smem[GV_F + (jl + 12) * 16 + bg];
            c_state = sigf(fv) * c_state + sigf(iv) * tanhf(gg);
            float hval = sigf(ov) * tanhf(c_state);
            float* hdst = hglob2 + ((size_t)(t & 1) << 14) +
                          ((col >> 6) << 10) + (bg << 6) + (col & 63);
            asm volatile("global_store_dword %0, %1, off sc0 sc1"
                         :: "v"(hdst), "v"(hval) : "memory");
            // split-bf16 hseq for next layer's MFMA GEMM (off critical path)
            unsigned short hh_ = f2bf(hval);
            unsigned short hl_ = f2bf(hval - bf2f(hh_));
            size_t idx = (size_t)(bg * TT + t) * HH + col;
            hseq_hi[idx] = hh_;
            hseq_lo[idx] = hl_;
        }

        if (t < TT - 1) {
            const unsigned target = wantbase + (unsigned)t + 1u;
            if (tid == 0) {
                asm volatile("s_waitcnt vmcnt(0)" ::: "memory");
                unsigned a = __hip_atomic_fetch_add(arr, 1u, __ATOMIC_RELAXED, __HIP_MEMORY_SCOPE_AGENT);
                if (a == 15u) {
                    unsigned ra = __hip_atomic_fetch_add(root, 1u, __ATOMIC_RELAXED, __HIP_MEMORY_SCOPE_AGENT);
                    if (ra == 15u) {
                        __hip_atomic_store(root, 0u, __ATOMIC_RELAXED, __HIP_MEMORY_SCOPE_AGENT);
#pragma unroll
                        for (int i = 0; i < 16; ++i)
                            __hip_atomic_store(bar + (i << 4), 0u, __ATOMIC_RELAXED, __HIP_MEMORY_SCOPE_AGENT);
                        asm volatile("s_waitcnt vmcnt(0)" ::: "memory");
#pragma unroll
                        for (int i = 0; i < 16; ++i)
                            __hip_atomic_store(bar + 512 + (i << 4), target,
                                               __ATOMIC_RELAXED, __HIP_MEMORY_SCOPE_AGENT);
                    }
                }
                while (__hip_atomic_load(genc, __ATOMIC_RELAXED, __HIP_MEMORY_SCOPE_AGENT) < target)
                    __builtin_amdgcn_s_sleep(1);
            }
            __syncthreads();
        }
        xg_pref = xg_next;
    }
}

// ---------------- FC head ----------------
__global__ void fc_relu_split(const ushort* __restrict__ ih, const ushort* __restrict__ il,
                              const float* __restrict__ w, const float* __restrict__ b,
                              float* __restrict__ out, int N, int K)
{
    int g = blockIdx.x * blockDim.x + threadIdx.x;
    if (g >= BB * N) return;
    int bi = g / N, n = g - bi * N;
    const ushort* ph = ih + (size_t)(bi * 256 + 255) * 1024;
    const ushort* pl = il + (size_t)(bi * 256 + 255) * 1024;
    const float* wp = w + (size_t)n * K;
    float s = 0.f;
    for (int k = 0; k < K; k += 4) {
        ushort4 uh = *(const ushort4*)(ph + k);
        ushort4 ul = *(const ushort4*)(pl + k);
        float4 q = *(const float4*)(wp + k);
        s += (bf2f(uh.x) + bf2f(ul.x)) * q.x + (bf2f(uh.y) + bf2f(ul.y)) * q.y +
             (bf2f(uh.z) + bf2f(ul.z)) * q.z + (bf2f(uh.w) + bf2f(ul.w)) * q.w;
    }
    s += b[n];
    out[g] = fmaxf(s, 0.f);
}

__global__ void fc_relu(const float* __restrict__ in, const float* __restrict__ w,
                        const float* __restrict__ b, float* __restrict__ out,
                        int N, int K, int do_relu)
{
    int g = blockIdx.x * blockDim.x + threadIdx.x;
    if (g >= BB * N) return;
    int bi = g / N, n = g - bi * N;
    const float* ip = in + (size_t)bi * K;
    const float* wp = w + (size_t)n * K;
    float s = 0.f;
    for (int k = 0; k < K; k += 4) {
        float4 a = *(const float4*)(ip + k);
        float4 q = *(const float4*)(wp + k);
        s += a.x * q.x + a.y * q.y + a.z * q.z + a.w * q.w;
    }
    s += b[n];
    if (do_relu) s = fmaxf(s, 0.f);
    out[g] = s;
}

// ---------------- launch ----------------
extern "C" void kernel_launch(void* const* d_in, const int* in_sizes, int n_in,
                              void* d_out, int out_size, void* d_ws, size_t ws_size,
                              hipStream_t stream)
{
    const float* x    = (const float*)d_in[0];
    const float* Wih0 = (const float*)d_in[1];
    const float* WihR = (const float*)d_in[2];
    const float* Whh  = (const float*)d_in[3];
    const float* bih  = (const float*)d_in[4];
    const float* bhh  = (const float*)d_in[5];
    const float* fc1w = (const float*)d_in[6];
    const float* fc1b = (const float*)d_in[7];
    const float* fc2w = (const float*)d_in[8];
    const float* fc2b = (const float*)d_in[9];
    const float* fc3w = (const float*)d_in[10];
    const float* fc3b = (const float*)d_in[11];
    float* out = (float*)d_out;
    char* ws = (char*)d_ws;

    float* xg     = (float*)(ws + XG_OFF);
    ushort* reg_[2] = {(ushort*)(ws + REG0_OFF), (ushort*)(ws + REG1_OFF)};
    float* hglob2 = (float*)(ws + HG2_OFF);
    float* fc1o   = (float*)(ws + FC1_OFF);
    float* fc2o   = (float*)(ws + FC2_OFF);
    unsigned* bar = (unsigned*)(ws + BAR_OFF);

    (void)hipFuncSetAttribute((const void*)lstm_scan,
                              hipFuncAttributeMaxDynamicSharedMemorySize, SMEM_BYTES);
    (void)hipMemsetAsync(ws + BAR_OFF, 0, 4096, stream);

    // layer-0 X conversion into region 1 (dead before Wcv(1) is written)
    ushort* xcv_hi = reg_[1];
    ushort* xcv_lo = reg_[1] + 2097152;
    conv_split<<<2048, 256, 0, stream>>>(x, xcv_hi, xcv_lo, (BB * TT * IN0) / 4);

    for (int l = 0; l < NLAYERS; ++l) {
        const int K = (l == 0) ? IN0 : HH;
        const float* Wl_f = (l == 0) ? Wih0 : (WihR + (size_t)(l - 1) * GG * HH);

        // W conversion into region l&1 (hs(l) will overwrite after GEMM l)
        ushort* wh = reg_[l & 1];
        ushort* wl = wh + 4194304;
        const int n4 = GG * K / 4;
        conv_split<<<(n4 + 255) / 256, 256, 0, stream>>>(Wl_f, wh, wl, n4);

        const ushort* ah = (l == 0) ? xcv_hi : reg_[(l - 1) & 1];
        const ushort* al = (l == 0) ? xcv_lo : (reg_[(l - 1) & 1] + 4194304);

        gemm_mfma<<<dim3(32, 32), 256, 0, stream>>>(
            ah, al, wh, wl, bih + (size_t)l * GG, bhh + (size_t)l * GG, xg, K);

        ushort* hs_hi = reg_[l & 1];
        ushort* hs_lo = reg_[l & 1] + 4194304;
        const float* whh_l = Whh + (size_t)l * GG * HH;
        unsigned wantbase = (unsigned)(TT * l);
        void* args[7] = {(void*)&whh_l, (void*)&xg, (void*)&hs_hi, (void*)&hs_lo,
                         (void*)&hglob2, (void*)&bar, (void*)&wantbase};
        hipError_t e = hipLaunchCooperativeKernel((void*)lstm_scan, dim3(NWG), dim3(256),
                                                  args, SMEM_BYTES, stream);
        if (e != hipSuccess) {
            lstm_scan<<<dim3(NWG), dim3(256), SMEM_BYTES, stream>>>(
                whh_l, xg, hs_hi, hs_lo, hglob2, bar, wantbase);
        }
    }

    // FC head: hs(7) is in region 1
    fc_relu_split<<<32, 256, 0, stream>>>(reg_[1], reg_[1] + 4194304,
                                          fc1w, fc1b, fc1o, 512, 1024);
    fc_relu<<<16, 256, 0, stream>>>(fc1o, fc2w, fc2b, fc2o, 256, 512, 1);
    fc_relu<<<1, 16, 0, stream>>>(fc2o, fc3w, fc3b, out, 1, 256, 0);
}